// Round 8
// baseline (243.754 us; speedup 1.0000x reference)
//
#include <hip/hip_runtime.h>
#include <hip/hip_fp16.h>

#define N_NODES 100000
#define N_EDGES 1600000
#define C 128

// binned CSR build (fixed-capacity buckets)
#define NB_SHIFT 10
#define NB (1 << NB_SHIFT)                        // 1024 nodes per bucket
#define NBKT ((N_NODES + NB - 1) >> NB_SHIFT)     // 98 buckets
#define CAP 20480                                 // edges per bucket window (avg 16327)
#define CPT 4096                                  // edges per stage block
#define STG_BLOCKS ((N_EDGES + CPT - 1) / CPT)    // 391
#define CVB 782                                   // cvt blocks (512 thr * 8 float4)
#define PWB 32                                    // prepw blocks

typedef _Float16 half8 __attribute__((ext_vector_type(8)));
typedef float f32x4 __attribute__((ext_vector_type(4)));

// ---------------- fused pre-pass: cvt | prepw | binned stage ----------------

__global__ __launch_bounds__(512) void k_fusedA(
    const float* __restrict__ x, const int* __restrict__ src,
    const int* __restrict__ dst, const float* __restrict__ Wl1,
    const float* __restrict__ Wr1, const float* __restrict__ Wl2,
    const float* __restrict__ Wr2, int* __restrict__ gcur,
    uint2* __restrict__ S, __half* __restrict__ Xh, __half* __restrict__ Wc1,
    __half* __restrict__ Wc2) {
    __shared__ int hist[128], sc[128], lstart[128], gbaseL[128];
    __shared__ uint2 stg[CPT];
    const int bid = blockIdx.x;
    const int t = threadIdx.x;

    if (bid < CVB) {
        const float4* xin = (const float4*)x;
        __half2* yout = (__half2*)Xh;
#pragma unroll
        for (int i = 0; i < 8; i++) {
            int idx = bid * 4096 + i * 512 + t;
            if (idx < N_NODES * C / 4) {
                float4 v = xin[idx];
                yout[idx * 2] = __floats2half2_rn(v.x, v.y);
                yout[idx * 2 + 1] = __floats2half2_rn(v.z, v.w);
            }
        }
        return;
    }
    if (bid < CVB + PWB) {
        int i0 = ((bid - CVB) * 512 + t) * 4;
#pragma unroll
        for (int m = 0; m < 4; m++) {
            int i = i0 + m;
            if (i < 2 * 128 * 256) {
                int set = i >> 15;
                int j = i & 32767;
                int n_ = j >> 8, k = j & 255;
                const float* Wl = set ? Wl2 : Wl1;
                const float* Wr = set ? Wr2 : Wr1;
                float v = (k < 128) ? Wl[n_ * 128 + k] : Wr[n_ * 128 + (k - 128)];
                (set ? Wc2 : Wc1)[j] = __float2half_rn(v);
            }
        }
        return;
    }

    // ---- binned stage ----
    int base = (bid - CVB - PWB) * CPT;
    int cnt = N_EDGES - base;
    if (cnt > CPT) cnt = CPT;
    if (t < 128) hist[t] = 0;
    __syncthreads();
    unsigned s_[8], d_[8];
    int r_[8], b_[8];
#pragma unroll
    for (int i = 0; i < 8; i++) {
        int li = i * 512 + t;
        if (li < cnt) {
            int e = base + li;
            s_[i] = src[e];
            d_[i] = dst[e];
            b_[i] = d_[i] >> NB_SHIFT;
            r_[i] = atomicAdd(&hist[b_[i]], 1);
        } else {
            r_[i] = -1;
        }
    }
    __syncthreads();
    int hv = (t < 128) ? hist[t] : 0;
    if (t < 128) sc[t] = hv;
    __syncthreads();
    for (int off = 1; off < 128; off <<= 1) {
        int u = (t < 128 && t >= off) ? sc[t - off] : 0;
        __syncthreads();
        if (t < 128) sc[t] += u;
        __syncthreads();
    }
    if (t < 128) lstart[t] = sc[t] - hv;
    if (t < NBKT && hv) gbaseL[t] = t * CAP + atomicAdd(&gcur[t], hv);
    __syncthreads();
#pragma unroll
    for (int i = 0; i < 8; i++)
        if (r_[i] >= 0) stg[lstart[b_[i]] + r_[i]] = make_uint2(s_[i], d_[i]);
    __syncthreads();
    for (int slot = t; slot < cnt; slot += 512) {
        uint2 ed = stg[slot];
        int b = ed.y >> NB_SHIFT;
        S[gbaseL[b] + (slot - lstart[b])] = ed;
    }
}

// ---- per-bucket fine counting sort -> rowbeg/rowend + col (gapped windows) ----
__global__ __launch_bounds__(1024) void k_bfine(const uint2* __restrict__ S,
                                                const int* __restrict__ gcur,
                                                int* __restrict__ rowbeg,
                                                int* __restrict__ rowend,
                                                int* __restrict__ col) {
    __shared__ int hist[NB];
    __shared__ int wsum[16];
    int t = threadIdx.x, b = blockIdx.x;
    int nbeg = b << NB_SHIFT;
    int ebeg = b * CAP;
    int cnt = gcur[b];
    hist[t] = 0;
    __syncthreads();
    for (int e = t; e < cnt; e += 1024) atomicAdd(&hist[S[ebeg + e].y - nbeg], 1);
    __syncthreads();
    int v = hist[t];
    int inc = v;
    int lane = t & 63, wid = t >> 6;
#pragma unroll
    for (int off = 1; off < 64; off <<= 1) {
        int u = __shfl_up(inc, off);
        if (lane >= off) inc += u;
    }
    if (lane == 63) wsum[wid] = inc;
    __syncthreads();
    if (t < 16) {
        int wi = wsum[t];
#pragma unroll
        for (int off = 1; off < 16; off <<= 1) {
            int u = __shfl_up(wi, off);
            if (t >= off) wi += u;
        }
        wsum[t] = wi;
    }
    __syncthreads();
    int woff = (wid == 0) ? 0 : wsum[wid - 1];
    int excl = inc - v + woff;
    int g = nbeg + t;
    if (g < N_NODES) {
        rowbeg[g] = ebeg + excl;
        rowend[g] = ebeg + excl + v;
    }
    __syncthreads();
    hist[t] = excl;
    __syncthreads();
    for (int e = t; e < cnt; e += 1024) {
        uint2 ed = S[ebeg + e];
        int p = atomicAdd(&hist[ed.y - nbeg], 1);
        col[ebeg + p] = ed.x;
    }
}

// ---------------- fused layer: mean-gather -> LDS -> MFMA GEMM (+relu, +head) ----
// 512 threads, 128 nodes/block. Phase 1: 32 lane-groups gather-mean into
// Ms[4][128][40] (MFMA A-fragment chunk layout). Phase 2: K=256 GEMM, 8 waves
// (2x4), wave tile 64x32; self-path A read direct from global (block-local
// 32KB slab), B-fragments direct from L2-hot 64KB packed W. No barriers in
// the GEMM phase; MFMA of this block overlaps other blocks' gathers.

template <int HEAD>
__global__ __launch_bounds__(512) void k_layer(
    const __half* __restrict__ Xg, const __half* __restrict__ W,
    const float* __restrict__ bias, const int* __restrict__ rowbeg,
    const int* __restrict__ rowend, const int* __restrict__ col,
    __half* __restrict__ Hout, const float* __restrict__ Wo,
    const float* __restrict__ bo, float* __restrict__ out) {
    __shared__ __half Ms[4][128][40];
    __shared__ float outs[4][128];
    const int tid = threadIdx.x;
    const int n0 = blockIdx.x * 128;

    // ---- phase 1: gather-mean ----
    {
        const int grp = tid >> 4, seg = tid & 15;
#pragma unroll
        for (int p = 0; p < 4; p++) {
            int ln = p * 32 + grp;
            int node = n0 + ln;
            float acc[8];
#pragma unroll
            for (int i = 0; i < 8; i++) acc[i] = 0.f;
            if (node < N_NODES) {
                int beg = rowbeg[node], end = rowend[node];
                for (int e = beg; e < end; e += 8) {
                    uint4 v[8];
                    bool val[8];
#pragma unroll
                    for (int u = 0; u < 8; u++) {
                        int ee = e + u;
                        val[u] = (ee < end);
                        int s = col[val[u] ? ee : (end - 1)];
                        v[u] = *(const uint4*)(Xg + (size_t)s * C + seg * 8);
                    }
#pragma unroll
                    for (int u = 0; u < 8; u++) {
                        if (val[u]) {
                            const __half2* h = (const __half2*)&v[u];
#pragma unroll
                            for (int q = 0; q < 4; q++) {
                                float2 f = __half22float2(h[q]);
                                acc[2 * q] += f.x;
                                acc[2 * q + 1] += f.y;
                            }
                        }
                    }
                }
                int deg = end - beg;
                float inv = 1.0f / (float)((deg > 0) ? deg : 1);
#pragma unroll
                for (int i = 0; i < 8; i++) acc[i] *= inv;
            }
            __half2 o[4];
#pragma unroll
            for (int q = 0; q < 4; q++)
                o[q] = __floats2half2_rn(acc[2 * q], acc[2 * q + 1]);
            *(uint4*)&Ms[seg >> 2][ln][(seg & 3) * 8] = *(uint4*)o;
        }
    }
    __syncthreads();

    // ---- phase 2: GEMM K=256 (chunks 0-3 self from global, 4-7 mean from LDS) ----
    const int wid = tid >> 6, lane = tid & 63;
    const int wr = wid >> 2, wc = wid & 3;
    const int l15 = lane & 15, lk = lane >> 4;

    f32x4 acc[4][2];
#pragma unroll
    for (int m = 0; m < 4; m++)
#pragma unroll
        for (int n = 0; n < 2; n++) acc[m][n] = (f32x4)(0.0f);

#pragma unroll
    for (int c = 0; c < 8; c++) {
        half8 af[4], bf[2];
#pragma unroll
        for (int m = 0; m < 4; m++) {
            int r = n0 + wr * 64 + m * 16 + l15;
            if (c < 4) {
                r = (r < N_NODES) ? r : (N_NODES - 1);
                af[m] = *(const half8*)(Xg + (size_t)r * C + c * 32 + lk * 8);
            } else {
                af[m] = *(const half8*)&Ms[c - 4][wr * 64 + m * 16 + l15][lk * 8];
            }
        }
#pragma unroll
        for (int n = 0; n < 2; n++)
            bf[n] = *(const half8*)(W + (size_t)(wc * 32 + n * 16 + l15) * 256 +
                                    c * 32 + lk * 8);
#pragma unroll
        for (int m = 0; m < 4; m++)
#pragma unroll
            for (int n = 0; n < 2; n++)
                acc[m][n] =
                    __builtin_amdgcn_mfma_f32_16x16x32_f16(af[m], bf[n], acc[m][n], 0, 0, 0);
    }

    // ---- epilogue: bias + relu ----
    float bv[2];
#pragma unroll
    for (int n = 0; n < 2; n++) bv[n] = bias[wc * 32 + n * 16 + l15];
#pragma unroll
    for (int m = 0; m < 4; m++)
#pragma unroll
        for (int n = 0; n < 2; n++)
#pragma unroll
            for (int r = 0; r < 4; r++)
                acc[m][n][r] = fmaxf(acc[m][n][r] + bv[n], 0.f);

    if (!HEAD) {
        // C/D layout: col = l15, row_local = m*16 + lk*4 + r
#pragma unroll
        for (int m = 0; m < 4; m++) {
#pragma unroll
            for (int r = 0; r < 4; r++) {
                int row = n0 + wr * 64 + m * 16 + lk * 4 + r;
                if (row < N_NODES) {
#pragma unroll
                    for (int n = 0; n < 2; n++)
                        Hout[(size_t)row * C + wc * 32 + n * 16 + l15] =
                            __float2half_rn(acc[m][n][r]);
                }
            }
        }
    } else {
        float wv[2];
#pragma unroll
        for (int n = 0; n < 2; n++) wv[n] = Wo[wc * 32 + n * 16 + l15];
#pragma unroll
        for (int m = 0; m < 4; m++) {
#pragma unroll
            for (int r = 0; r < 4; r++) {
                float p = acc[m][0][r] * wv[0] + acc[m][1][r] * wv[1];
                p += __shfl_xor(p, 1);
                p += __shfl_xor(p, 2);
                p += __shfl_xor(p, 4);
                p += __shfl_xor(p, 8);
                if (l15 == 0) outs[wc][wr * 64 + m * 16 + lk * 4 + r] = p;
            }
        }
        __syncthreads();
        if (tid < 128) {
            int n_ = n0 + tid;
            if (n_ < N_NODES)
                out[n_] = outs[0][tid] + outs[1][tid] + outs[2][tid] + outs[3][tid] +
                          bo[0];
        }
    }
}

// ---------------- launch ----------------

extern "C" void kernel_launch(void* const* d_in, const int* in_sizes, int n_in,
                              void* d_out, int out_size, void* d_ws, size_t ws_size,
                              hipStream_t stream) {
    const float* x   = (const float*)d_in[0];
    const int*   ei  = (const int*)d_in[1];
    const float* Wl1 = (const float*)d_in[2];
    const float* bl1 = (const float*)d_in[3];
    const float* Wr1 = (const float*)d_in[4];
    const float* Wl2 = (const float*)d_in[5];
    const float* bl2 = (const float*)d_in[6];
    const float* Wr2 = (const float*)d_in[7];
    const float* Wo  = (const float*)d_in[8];
    const float* bo  = (const float*)d_in[9];
    float* out = (float*)d_out;

    const int* src = ei;
    const int* dst = ei + N_EDGES;

    char* ws = (char*)d_ws;
    auto carve = [&](size_t bytes) {
        char* p = ws;
        ws += (bytes + 1023) & ~(size_t)1023;
        return p;
    };
    int*    gcur   = (int*)carve((size_t)NBKT * 4);
    int*    rowbeg = (int*)carve((size_t)N_NODES * 4);
    int*    rowend = (int*)carve((size_t)N_NODES * 4);
    int*    col    = (int*)carve((size_t)NBKT * CAP * 4);
    uint2*  S      = (uint2*)carve((size_t)NBKT * CAP * 8);
    __half* Xh     = (__half*)carve((size_t)N_NODES * C * 2);
    __half* Hh     = (__half*)carve((size_t)N_NODES * C * 2);
    __half* Wc1    = (__half*)carve((size_t)128 * 256 * 2);
    __half* Wc2    = (__half*)carve((size_t)128 * 256 * 2);

    hipMemsetAsync(gcur, 0, (size_t)NBKT * 4, stream);

    // fused cvt + weight-pack + binned stage
    k_fusedA<<<CVB + PWB + STG_BLOCKS, 512, 0, stream>>>(
        x, src, dst, Wl1, Wr1, Wl2, Wr2, gcur, S, Xh, Wc1, Wc2);
    // per-bucket counting sort -> rowbeg/rowend + col
    k_bfine<<<NBKT, 1024, 0, stream>>>(S, gcur, rowbeg, rowend, col);

    dim3 gL((N_NODES + 127) / 128), b512(512);

    // layer 1 (mean + gemm + relu)
    k_layer<0><<<gL, b512, 0, stream>>>(Xh, Wc1, bl1, rowbeg, rowend, col, Hh,
                                        nullptr, nullptr, nullptr);
    // layer 2 (mean + gemm + relu + head)
    k_layer<1><<<gL, b512, 0, stream>>>(Hh, Wc2, bl2, rowbeg, rowend, col, nullptr,
                                        Wo, bo, out);
}